// Round 1
// baseline (640.623 us; speedup 1.0000x reference)
//
#include <hip/hip_runtime.h>
#include <stdint.h>

typedef __bf16 bf16x8 __attribute__((ext_vector_type(8)));
typedef float floatx4 __attribute__((ext_vector_type(4)));

__device__ __forceinline__ void gload_lds16(const void* g, void* l) {
    __builtin_amdgcn_global_load_lds((const __attribute__((address_space(1))) void*)g,
                                     (__attribute__((address_space(3))) void*)l, 16, 0, 0);
}

__device__ __forceinline__ uint16_t f2bf(float f) {
    uint32_t u = __float_as_uint(f);
    u += 0x7fff + ((u >> 16) & 1);   // RNE
    return (uint16_t)(u >> 16);
}

// ---- prep kernels ---------------------------------------------------------

// x [12,512,2048] f32 -> xpad [12,514,2048] bf16 (zero at tt=0 and tt=513)
__global__ void k_pad_x(const float* __restrict__ x, uint16_t* __restrict__ xpad) {
    int idx = blockIdx.x * 256 + threadIdx.x;       // < 12*514*2048
    int i   = idx & 2047;
    int tmp = idx >> 11;                            // b*514 + tt
    int b   = tmp / 514;
    int tt  = tmp - b * 514;
    float v = 0.0f;
    if (tt >= 1 && tt <= 512)
        v = x[((size_t)(b * 512 + tt - 1) << 11) + i];
    xpad[idx] = f2bf(v);
}

// conv_w [o][i][h] f32 -> wT [o][h*2048+i] bf16  (B^T layout for the GEMM)
__global__ void k_wT(const float* __restrict__ w, uint16_t* __restrict__ wT) {
    int o = blockIdx.x;
    const float* src = w + (size_t)o * 6144;
    uint16_t*    dst = wT + (size_t)o * 6144;
    for (int it = 0; it < 24; ++it) {
        int j = it * 256 + threadIdx.x;             // j = i*3 + h
        float v = src[j];
        int i = j / 3;
        int h = j - i * 3;
        dst[h * 2048 + i] = f2bf(v);
    }
}

// dst[c][r] = bf16(src[r][c]), R=C=2048 here; 64x64 LDS tiles
__global__ void k_transpose_bf16(const float* __restrict__ src, uint16_t* __restrict__ dst,
                                 int R, int C) {
    __shared__ float tile[64][65];
    int bx = blockIdx.x, by = blockIdx.y;
    int tx = threadIdx.x & 63, ty = threadIdx.x >> 6;
    for (int rr = ty; rr < 64; rr += 4)
        tile[rr][tx] = src[(size_t)(by * 64 + rr) * C + bx * 64 + tx];
    __syncthreads();
    for (int rr = ty; rr < 64; rr += 4)
        dst[(size_t)(bx * 64 + rr) * R + by * 64 + tx] = f2bf(tile[tx][rr]);
}

__global__ void k_f2bf(const float* __restrict__ s, uint16_t* __restrict__ d, int n) {
    int idx = blockIdx.x * 256 + threadIdx.x;
    if (idx < n) d[idx] = f2bf(s[idx]);
}

// a = rownorm(max(adj,adj^T) + I), one block per (b,i) row
__global__ void k_norm_adj(const float* __restrict__ adj, float* __restrict__ out) {
    int i = blockIdx.x, b = blockIdx.y, j = threadIdx.x;
    const float* A = adj + ((size_t)b << 16);
    float aij = A[(i << 8) + j];
    float aji = A[(j << 8) + i];
    float v = aji > aij ? aji : aij;
    if (j == i) v += 1.0f;
    float s = v;
    #pragma unroll
    for (int off = 32; off > 0; off >>= 1) s += __shfl_down(s, off);
    __shared__ float part[4];
    __shared__ float inv;
    if ((j & 63) == 0) part[j >> 6] = s;
    __syncthreads();
    if (j == 0) {
        float t = part[0] + part[1] + part[2] + part[3];
        inv = t > 0.0f ? 1.0f / t : 0.0f;
    }
    __syncthreads();
    out[((size_t)b << 16) + (i << 8) + j] = v * inv;
}

// ---- MFMA GEMM: C[M][N] = A[M][K] @ BT[N][K]^T, optional bias+relu --------
// 128x128 tile, BK=32, 256 threads = 4 waves (2x2), 16x16x32 bf16 MFMA.
// CONV=true: A rows address xpad with the k->(h,i) shift (implicit im2col).
template<bool CONV>
__global__ __launch_bounds__(256)
void k_gemm(const uint16_t* __restrict__ A, const uint16_t* __restrict__ BT,
            float* __restrict__ C, const float* __restrict__ bias,
            int M, int N, int K, int relu)
{
    __shared__ __align__(16) uint16_t As[128 * 32];
    __shared__ __align__(16) uint16_t Bs[128 * 32];
    const int tid  = threadIdx.x;
    const int rt   = blockIdx.y * 128;
    const int ct   = blockIdx.x * 128;
    const int lane = tid & 63;
    const int wave = tid >> 6;
    const int wm   = (wave >> 1) * 64;
    const int wn   = (wave & 1) * 64;
    const int lm   = lane & 15;
    const int kq   = (lane >> 4) * 8;
    const int srow  = tid >> 2;          // 0..63
    const int skcol = (tid & 3) * 8;     // 0,8,16,24

    floatx4 acc[4][4] = {};

    for (int k0 = 0; k0 < K; k0 += 32) {
        #pragma unroll
        for (int ii = 0; ii < 2; ++ii) {
            int row = ii * 64 + srow;
            const uint16_t* gsrc;
            if (CONV) {
                int r  = rt + row;
                int b  = r >> 9;
                int t  = r & 511;
                int kk = k0 + skcol;
                int h  = kk >> 11;
                int ic = kk & 2047;
                gsrc = A + ((size_t)(b * 514 + t + h) << 11) + ic;
            } else {
                gsrc = A + (size_t)(rt + row) * K + k0 + skcol;
            }
            gload_lds16(gsrc, &As[ii * 2048 + tid * 8]);
            gload_lds16(BT + (size_t)(ct + row) * K + k0 + skcol, &Bs[ii * 2048 + tid * 8]);
        }
        __syncthreads();

        bf16x8 af[4], bfr[4];
        #pragma unroll
        for (int mt = 0; mt < 4; ++mt)
            af[mt] = *(const bf16x8*)&As[(wm + mt * 16 + lm) * 32 + kq];
        #pragma unroll
        for (int nt = 0; nt < 4; ++nt)
            bfr[nt] = *(const bf16x8*)&Bs[(wn + nt * 16 + lm) * 32 + kq];
        #pragma unroll
        for (int mt = 0; mt < 4; ++mt)
            #pragma unroll
            for (int nt = 0; nt < 4; ++nt)
                acc[mt][nt] = __builtin_amdgcn_mfma_f32_16x16x32_bf16(af[mt], bfr[nt], acc[mt][nt], 0, 0, 0);
        __syncthreads();
    }

    const int lq = lane >> 4;
    #pragma unroll
    for (int mt = 0; mt < 4; ++mt) {
        #pragma unroll
        for (int nt = 0; nt < 4; ++nt) {
            int col = ct + wn + nt * 16 + lm;
            float bv = bias ? bias[col] : 0.0f;
            #pragma unroll
            for (int r = 0; r < 4; ++r) {
                int row = rt + wm + mt * 16 + lq * 4 + r;
                float v = acc[mt][nt][r] + bv;
                if (relu) v = fmaxf(v, 0.0f);
                C[(size_t)row * N + col] = v;
            }
        }
    }
}

// ---- sparse a @ H (+bias, optional relu), H f32 [1024][2048] --------------
template<bool RELU, bool OUTBF>
__global__ void k_amul(const float* __restrict__ a, const float* __restrict__ H,
                       const float* __restrict__ bias, void* __restrict__ outp)
{
    int f = blockIdx.x * 256 + threadIdx.x;
    int i = blockIdx.y;
    int b = blockIdx.z;
    __shared__ float arow[256];
    arow[threadIdx.x] = a[(((size_t)b << 8) + i) * 256 + threadIdx.x];
    __syncthreads();
    float s = 0.0f;
    const float* Hb = H + (((size_t)b << 8)) * 2048;
    for (int j = 0; j < 256; ++j) {
        float aij = arow[j];          // block-uniform -> no divergence
        if (aij != 0.0f)
            s += aij * Hb[(size_t)j * 2048 + f];
    }
    s += bias[f];
    if (RELU) s = fmaxf(s, 0.0f);
    size_t off = (((size_t)b << 8) + i) * 2048 + f;
    if (OUTBF) ((uint16_t*)outp)[off] = f2bf(s);
    else       ((float*)outp)[off]    = s;
}

// ---- launch ---------------------------------------------------------------

extern "C" void kernel_launch(void* const* d_in, const int* in_sizes, int n_in,
                              void* d_out, int out_size, void* d_ws, size_t ws_size,
                              hipStream_t stream)
{
    const float* x      = (const float*)d_in[0];
    const float* nodes  = (const float*)d_in[1];
    const float* adj    = (const float*)d_in[2];
    const float* conv_w = (const float*)d_in[3];
    const float* conv_b = (const float*)d_in[4];
    const float* W1     = (const float*)d_in[5];
    const float* b1     = (const float*)d_in[6];
    const float* W2     = (const float*)d_in[7];
    const float* b2     = (const float*)d_in[8];
    float* out = (float*)d_out;

    char* ws = (char*)d_ws;
    uint16_t* xpad   = (uint16_t*)(ws);                 // 12*514*2048*2 = 25,288,704
    uint16_t* wmT    = (uint16_t*)(ws + 25288704);      // 6144*2048*2  = 25,165,824
    uint16_t* W1T    = (uint16_t*)(ws + 50454528);      // 8,388,608
    uint16_t* W2T    = (uint16_t*)(ws + 58843136);      // 8,388,608
    uint16_t* nodesb = (uint16_t*)(ws + 67231744);      // 4,194,304
    float*    anorm  = (float*)   (ws + 71426048);      // 1,048,576
    float*    h1     = (float*)   (ws + 72474624);      // 8,388,608
    uint16_t* hb     = (uint16_t*)(ws + 80863232);      // 4,194,304
    float*    h2     = (float*)   (ws + 85057536);      // 8,388,608  (end ~93.4 MB)

    k_pad_x<<<49344, 256, 0, stream>>>(x, xpad);
    k_wT<<<2048, 256, 0, stream>>>(conv_w, wmT);
    k_transpose_bf16<<<dim3(32, 32), 256, 0, stream>>>(W1, W1T, 2048, 2048);
    k_transpose_bf16<<<dim3(32, 32), 256, 0, stream>>>(W2, W2T, 2048, 2048);
    k_f2bf<<<8192, 256, 0, stream>>>(nodes, nodesb, 1024 * 2048);
    k_norm_adj<<<dim3(256, 4), 256, 0, stream>>>(adj, anorm);

    // feats = relu(conv(x) + conv_b)  -> d_out[0 : 12582912)
    k_gemm<true><<<dim3(16, 48), 256, 0, stream>>>(xpad, wmT, out, conv_b, 6144, 2048, 6144, 1);
    // h1 = nodes @ W1 (batches stacked: [1024][2048])
    k_gemm<false><<<dim3(16, 8), 256, 0, stream>>>(nodesb, W1T, h1, nullptr, 1024, 2048, 2048, 0);
    // h = relu(a @ h1 + b1) -> bf16
    k_amul<true, true><<<dim3(8, 256, 4), 256, 0, stream>>>(anorm, h1, b1, hb);
    // h2 = h @ W2
    k_gemm<false><<<dim3(16, 8), 256, 0, stream>>>(hb, W2T, h2, nullptr, 1024, 2048, 2048, 0);
    // out = a @ h2 + b2 -> d_out[12582912 : )
    k_amul<false, false><<<dim3(8, 256, 4), 256, 0, stream>>>(anorm, h2, b2, out + 12582912);
}

// Round 2
// 506.546 us; speedup vs baseline: 1.2647x; 1.2647x over previous
//
#include <hip/hip_runtime.h>
#include <stdint.h>

typedef __bf16 bf16x8 __attribute__((ext_vector_type(8)));
typedef float floatx4 __attribute__((ext_vector_type(4)));

__device__ __forceinline__ void gload_lds16(const void* g, void* l) {
    __builtin_amdgcn_global_load_lds((const __attribute__((address_space(1))) void*)g,
                                     (__attribute__((address_space(3))) void*)l, 16, 0, 0);
}

__device__ __forceinline__ uint16_t f2bf(float f) {
    uint32_t u = __float_as_uint(f);
    u += 0x7fff + ((u >> 16) & 1);   // RNE
    return (uint16_t)(u >> 16);
}
__device__ __forceinline__ uint32_t f2bf2(float lo, float hi) {
    return (uint32_t)f2bf(lo) | ((uint32_t)f2bf(hi) << 16);
}

// ---- prep kernels ---------------------------------------------------------

// x [12,512,2048] f32 -> xpad [12,514,2048] bf16 (zero rows at tt=0, tt=513)
// 2 elements/thread, uint32 stores.
__global__ void k_pad_x(const float* __restrict__ x, uint32_t* __restrict__ xpad) {
    int idx2 = blockIdx.x * 256 + threadIdx.x;      // pair index < 12*514*1024
    int i2   = idx2 & 1023;
    int tmp  = idx2 >> 10;                          // b*514 + tt
    int b    = tmp / 514;
    int tt   = tmp - b * 514;
    float lo = 0.0f, hi = 0.0f;
    if (tt >= 1 && tt <= 512) {
        const float* s = x + ((size_t)(b * 512 + tt - 1) << 11) + i2 * 2;
        lo = s[0]; hi = s[1];
    }
    xpad[idx2] = f2bf2(lo, hi);
}

// conv_w [o][i][h] f32 -> wT [o][h*2048+i] bf16, LDS-staged so writes coalesce
__global__ void k_wT(const float* __restrict__ w, uint16_t* __restrict__ wT) {
    __shared__ float buf[6144];
    int o = blockIdx.x;
    const float* src = w + (size_t)o * 6144;
    uint16_t*    dst = wT + (size_t)o * 6144;
    #pragma unroll
    for (int it = 0; it < 24; ++it)
        buf[it * 256 + threadIdx.x] = src[it * 256 + threadIdx.x];
    __syncthreads();
    #pragma unroll
    for (int h = 0; h < 3; ++h)
        #pragma unroll
        for (int c = 0; c < 8; ++c) {
            int i = c * 256 + threadIdx.x;
            dst[h * 2048 + i] = f2bf(buf[i * 3 + h]);   // stride-3 LDS: conflict-free
        }
}

// dst[c][r] = bf16(src[r][c]); z selects (W1->W1T) or (W2->W2T)
__global__ void k_transpose_bf16(const float* __restrict__ W1, const float* __restrict__ W2,
                                 uint16_t* __restrict__ W1T, uint16_t* __restrict__ W2T) {
    __shared__ float tile[64][65];
    const float* src = blockIdx.z ? W2 : W1;
    uint16_t*    dst = blockIdx.z ? W2T : W1T;
    int bx = blockIdx.x, by = blockIdx.y;
    int tx = threadIdx.x & 63, ty = threadIdx.x >> 6;
    for (int rr = ty; rr < 64; rr += 4)
        tile[rr][tx] = src[(size_t)(by * 64 + rr) * 2048 + bx * 64 + tx];
    __syncthreads();
    for (int rr = ty; rr < 64; rr += 4)
        dst[(size_t)(bx * 64 + rr) * 2048 + by * 64 + tx] = f2bf(tile[tx][rr]);
}

__global__ void k_f2bf(const float* __restrict__ s, uint32_t* __restrict__ d) {
    int idx2 = blockIdx.x * 256 + threadIdx.x;
    d[idx2] = f2bf2(s[idx2 * 2], s[idx2 * 2 + 1]);
}

// a = rownorm(max(adj,adj^T) + I), compacted to CSR-ish (nnz<=256 per row)
__global__ void k_norm_adj(const float* __restrict__ adj, float* __restrict__ aval,
                           uint16_t* __restrict__ aidx, int* __restrict__ annz) {
    int i = blockIdx.x, b = blockIdx.y, j = threadIdx.x;
    const float* A = adj + ((size_t)b << 16);
    float aij = A[(i << 8) + j];
    float aji = A[(j << 8) + i];
    float v = fmaxf(aij, aji);
    if (j == i) v += 1.0f;

    float s = v;
    #pragma unroll
    for (int off = 32; off > 0; off >>= 1) s += __shfl_down(s, off);

    bool pred = v != 0.0f;
    unsigned long long m = __ballot(pred);
    int wid = j >> 6;

    __shared__ float part[4];
    __shared__ int   wcnt[4];
    __shared__ int   woff[4];
    __shared__ float sinv;
    if ((j & 63) == 0) { part[wid] = s; wcnt[wid] = (int)__popcll(m); }
    __syncthreads();
    int row = (b << 8) + i;
    if (j == 0) {
        float t = part[0] + part[1] + part[2] + part[3];
        sinv = t > 0.0f ? 1.0f / t : 0.0f;
        int o = 0;
        #pragma unroll
        for (int w = 0; w < 4; ++w) { woff[w] = o; o += wcnt[w]; }
        annz[row] = o;
    }
    __syncthreads();
    if (pred) {
        int pos = woff[wid] + (int)__popcll(m & ((1ull << (j & 63)) - 1ull));
        aval[row * 256 + pos] = v * sinv;
        aidx[row * 256 + pos] = (uint16_t)j;
    }
}

// ---- MFMA GEMM: C[M][N] = A[M][K] @ BT[N][K]^T ----------------------------
// 128x128 tile, BK=32, 256 threads = 4 waves (2x2), 16x16x32 bf16 MFMA.
// CONV: implicit im2col addressing into xpad. SPLIT>1: K split over blockIdx.z,
// f32 atomicAdd epilogue into pre-zeroed C (no bias/relu).
template<bool CONV, int SPLIT>
__global__ __launch_bounds__(256)
void k_gemm(const uint16_t* __restrict__ A, const uint16_t* __restrict__ BT,
            float* __restrict__ C, const float* __restrict__ bias,
            int M, int N, int K, int relu)
{
    __shared__ __align__(16) uint16_t As[128 * 32];
    __shared__ __align__(16) uint16_t Bs[128 * 32];
    const int tid  = threadIdx.x;
    const int rt   = blockIdx.y * 128;
    const int ct   = blockIdx.x * 128;
    const int lane = tid & 63;
    const int wave = tid >> 6;
    const int wm   = (wave >> 1) * 64;
    const int wn   = (wave & 1) * 64;
    const int lm   = lane & 15;
    const int kq   = (lane >> 4) * 8;
    const int srow  = tid >> 2;          // 0..63
    const int skcol = (tid & 3) * 8;     // 0,8,16,24

    const int kchunk = K / SPLIT;
    const int kbeg   = (SPLIT > 1) ? blockIdx.z * kchunk : 0;

    floatx4 acc[4][4] = {};

    for (int k0 = kbeg; k0 < kbeg + kchunk; k0 += 32) {
        #pragma unroll
        for (int ii = 0; ii < 2; ++ii) {
            int row = ii * 64 + srow;
            const uint16_t* gsrc;
            if (CONV) {
                int r  = rt + row;
                int b  = r >> 9;
                int t  = r & 511;
                int kk = k0 + skcol;
                int h  = kk >> 11;
                int ic = kk & 2047;
                gsrc = A + ((size_t)(b * 514 + t + h) << 11) + ic;
            } else {
                gsrc = A + (size_t)(rt + row) * K + k0 + skcol;
            }
            gload_lds16(gsrc, &As[ii * 2048 + tid * 8]);
            gload_lds16(BT + (size_t)(ct + row) * K + k0 + skcol, &Bs[ii * 2048 + tid * 8]);
        }
        __syncthreads();

        bf16x8 af[4], bfr[4];
        #pragma unroll
        for (int mt = 0; mt < 4; ++mt)
            af[mt] = *(const bf16x8*)&As[(wm + mt * 16 + lm) * 32 + kq];
        #pragma unroll
        for (int nt = 0; nt < 4; ++nt)
            bfr[nt] = *(const bf16x8*)&Bs[(wn + nt * 16 + lm) * 32 + kq];
        #pragma unroll
        for (int mt = 0; mt < 4; ++mt)
            #pragma unroll
            for (int nt = 0; nt < 4; ++nt)
                acc[mt][nt] = __builtin_amdgcn_mfma_f32_16x16x32_bf16(af[mt], bfr[nt], acc[mt][nt], 0, 0, 0);
        __syncthreads();
    }

    const int lq = lane >> 4;
    #pragma unroll
    for (int mt = 0; mt < 4; ++mt) {
        #pragma unroll
        for (int nt = 0; nt < 4; ++nt) {
            int col = ct + wn + nt * 16 + lm;
            float bv = (SPLIT == 1 && bias) ? bias[col] : 0.0f;
            #pragma unroll
            for (int r = 0; r < 4; ++r) {
                int row = rt + wm + mt * 16 + lq * 4 + r;
                if (SPLIT == 1) {
                    float v = acc[mt][nt][r] + bv;
                    if (relu) v = fmaxf(v, 0.0f);
                    C[(size_t)row * N + col] = v;
                } else {
                    atomicAdd(&C[(size_t)row * N + col], acc[mt][nt][r]);
                }
            }
        }
    }
}

// ---- sparse a @ H (+bias, optional relu) over CSR, H f32 [1024][2048] -----
template<bool RELU, bool OUTBF>
__global__ void k_amul(const float* __restrict__ aval, const uint16_t* __restrict__ aidx,
                       const int* __restrict__ annz, const float* __restrict__ H,
                       const float* __restrict__ bias, void* __restrict__ outp)
{
    int f = blockIdx.x * 256 + threadIdx.x;
    int i = blockIdx.y;
    int b = blockIdx.z;
    int row = (b << 8) + i;
    __shared__ float vv[256];
    __shared__ int   jj[256];
    int n0 = annz[row];
    vv[threadIdx.x] = aval[row * 256 + threadIdx.x];
    jj[threadIdx.x] = aidx[row * 256 + threadIdx.x];
    __syncthreads();
    const float* Hb = H + ((size_t)b << 8) * 2048;
    float s = 0.0f;
    #pragma unroll 4
    for (int c = 0; c < n0; ++c)
        s += vv[c] * Hb[(size_t)jj[c] * 2048 + f];
    s += bias[f];
    if (RELU) s = fmaxf(s, 0.0f);
    size_t off = ((size_t)row) * 2048 + f;
    if (OUTBF) ((uint16_t*)outp)[off] = f2bf(s);
    else       ((float*)outp)[off]    = s;
}

// ---- launch ---------------------------------------------------------------

extern "C" void kernel_launch(void* const* d_in, const int* in_sizes, int n_in,
                              void* d_out, int out_size, void* d_ws, size_t ws_size,
                              hipStream_t stream)
{
    const float* x      = (const float*)d_in[0];
    const float* nodes  = (const float*)d_in[1];
    const float* adj    = (const float*)d_in[2];
    const float* conv_w = (const float*)d_in[3];
    const float* conv_b = (const float*)d_in[4];
    const float* W1     = (const float*)d_in[5];
    const float* b1     = (const float*)d_in[6];
    const float* W2     = (const float*)d_in[7];
    const float* b2     = (const float*)d_in[8];
    float* out = (float*)d_out;

    char* ws = (char*)d_ws;
    uint16_t* xpad   = (uint16_t*)(ws);                 // 25,288,704
    uint16_t* wmT    = (uint16_t*)(ws + 25288704);      // 25,165,824
    uint16_t* W1T    = (uint16_t*)(ws + 50454528);      // 8,388,608
    uint16_t* W2T    = (uint16_t*)(ws + 58843136);      // 8,388,608
    uint16_t* nodesb = (uint16_t*)(ws + 67231744);      // 4,194,304
    float*    aval   = (float*)   (ws + 71426048);      // 1,048,576
    float*    h1     = (float*)   (ws + 72474624);      // 8,388,608
    uint16_t* hb     = (uint16_t*)(ws + 80863232);      // 4,194,304
    float*    h2     = (float*)   (ws + 85057536);      // 8,388,608
    uint16_t* aidx   = (uint16_t*)(ws + 93446144);      // 524,288
    int*      annz   = (int*)     (ws + 93970432);      // 4,096  (end ~94 MB)

    // zero split-K accumulators (graph-capturable stream op)
    hipMemsetAsync(h1, 0, 8388608, stream);
    hipMemsetAsync(h2, 0, 8388608, stream);

    k_pad_x<<<24672, 256, 0, stream>>>(x, (uint32_t*)xpad);
    k_wT<<<2048, 256, 0, stream>>>(conv_w, wmT);
    k_transpose_bf16<<<dim3(32, 32, 2), 256, 0, stream>>>(W1, W2, W1T, W2T);
    k_f2bf<<<4096, 256, 0, stream>>>(nodes, (uint32_t*)nodesb);
    k_norm_adj<<<dim3(256, 4), 256, 0, stream>>>(adj, aval, aidx, annz);

    // feats = relu(conv(x) + conv_b)  -> d_out[0 : 12582912)
    k_gemm<true, 1><<<dim3(16, 48), 256, 0, stream>>>(xpad, wmT, out, conv_b, 6144, 2048, 6144, 1);
    // h1 = nodes @ W1 (split-K=4, atomic accumulate)
    k_gemm<false, 4><<<dim3(16, 8, 4), 256, 0, stream>>>(nodesb, W1T, h1, nullptr, 1024, 2048, 2048, 0);
    // h = relu(a @ h1 + b1) -> bf16
    k_amul<true, true><<<dim3(8, 256, 4), 256, 0, stream>>>(aval, aidx, annz, h1, b1, hb);
    // h2 = h @ W2 (split-K=4)
    k_gemm<false, 4><<<dim3(16, 8, 4), 256, 0, stream>>>(hb, W2T, h2, nullptr, 1024, 2048, 2048, 0);
    // out = a @ h2 + b2 -> d_out[12582912 : )
    k_amul<false, false><<<dim3(8, 256, 4), 256, 0, stream>>>(aval, aidx, annz, h2, b2, out + 12582912);
}

// Round 3
// 475.156 us; speedup vs baseline: 1.3482x; 1.0661x over previous
//
#include <hip/hip_runtime.h>
#include <stdint.h>

typedef __bf16 bf16x8 __attribute__((ext_vector_type(8)));
typedef float floatx4 __attribute__((ext_vector_type(4)));

__device__ __forceinline__ void gload_lds16(const void* g, void* l) {
    __builtin_amdgcn_global_load_lds((const __attribute__((address_space(1))) void*)g,
                                     (__attribute__((address_space(3))) void*)l, 16, 0, 0);
}

__device__ __forceinline__ uint16_t f2bf(float f) {
    uint32_t u = __float_as_uint(f);
    u += 0x7fff + ((u >> 16) & 1);   // RNE
    return (uint16_t)(u >> 16);
}
__device__ __forceinline__ uint32_t f2bf2(float lo, float hi) {
    return (uint32_t)f2bf(lo) | ((uint32_t)f2bf(hi) << 16);
}

// ---- fused prep: pad_x | wT | W-transpose | nodes cast | norm_adj ---------
// Block ranges (1D grid):
//   [0, 24672)          pad_x      (12*514*1024 pairs / 256)
//   [24672, 26720)      wT         (2048 output rows)
//   [26720, 28768)      W1/W2 transpose (2 * 32 * 32 tiles)
//   [28768, 32864)      nodes f2bf (1,048,576 pairs / 256)
//   [32864, 33888)      norm_adj   (4 * 256 rows)
#define PREP_NP 24672
#define PREP_NW 26720
#define PREP_NT 28768
#define PREP_NF 32864
#define PREP_NA 33888

__global__ __launch_bounds__(256)
void k_prep(const float* __restrict__ x, uint32_t* __restrict__ xpad,
            const float* __restrict__ w, uint16_t* __restrict__ wT,
            const float* __restrict__ W1, const float* __restrict__ W2,
            uint16_t* __restrict__ W1T, uint16_t* __restrict__ W2T,
            const float* __restrict__ nodes, uint32_t* __restrict__ nodesb,
            const float* __restrict__ adj, float* __restrict__ aval,
            uint16_t* __restrict__ aidx, int* __restrict__ annz)
{
    __shared__ union {
        float wbuf[6144];
        float tile[64][65];
        struct { float part[4]; int wcnt[4]; int woff[4]; float sinv; } na;
    } sm;
    const int bid = blockIdx.x;
    const int tid = threadIdx.x;

    if (bid < PREP_NP) {
        // ---- x [12,512,2048] f32 -> xpad [12,514,2048] bf16 (zero pad rows)
        int idx2 = bid * 256 + tid;
        int i2   = idx2 & 1023;
        int tmp  = idx2 >> 10;                      // b*514 + tt
        int b    = tmp / 514;
        int tt   = tmp - b * 514;
        float lo = 0.0f, hi = 0.0f;
        if (tt >= 1 && tt <= 512) {
            const float* s = x + ((size_t)(b * 512 + tt - 1) << 11) + i2 * 2;
            lo = s[0]; hi = s[1];
        }
        xpad[idx2] = f2bf2(lo, hi);
    } else if (bid < PREP_NW) {
        // ---- conv_w [o][i][h] -> wT [o][h*2048+i] bf16 (LDS-staged)
        int o = bid - PREP_NP;
        const float* src = w + (size_t)o * 6144;
        uint16_t*    dst = wT + (size_t)o * 6144;
        #pragma unroll
        for (int it = 0; it < 24; ++it)
            sm.wbuf[it * 256 + tid] = src[it * 256 + tid];
        __syncthreads();
        #pragma unroll
        for (int h = 0; h < 3; ++h)
            #pragma unroll
            for (int c = 0; c < 8; ++c) {
                int i = c * 256 + tid;
                dst[h * 2048 + i] = f2bf(sm.wbuf[i * 3 + h]);  // stride-3: conflict-free
            }
    } else if (bid < PREP_NT) {
        // ---- W1/W2 [2048][2048] -> bf16 transpose
        int t  = bid - PREP_NW;
        int z  = t >> 10;
        int by = (t >> 5) & 31;
        int bx = t & 31;
        const float* src = z ? W2 : W1;
        uint16_t*    dst = z ? W2T : W1T;
        int tx = tid & 63, ty = tid >> 6;
        for (int rr = ty; rr < 64; rr += 4)
            sm.tile[rr][tx] = src[(size_t)(by * 64 + rr) * 2048 + bx * 64 + tx];
        __syncthreads();
        for (int rr = ty; rr < 64; rr += 4)
            dst[(size_t)(bx * 64 + rr) * 2048 + by * 64 + tx] = f2bf(sm.tile[tx][rr]);
    } else if (bid < PREP_NF) {
        // ---- nodes f32 -> bf16
        int idx2 = (bid - PREP_NT) * 256 + tid;
        nodesb[idx2] = f2bf2(nodes[idx2 * 2], nodes[idx2 * 2 + 1]);
    } else {
        // ---- a = rownorm(max(adj,adj^T) + I), CSR-compacted
        int t = bid - PREP_NF;
        int i = t & 255, b = t >> 8, j = tid;
        const float* A = adj + ((size_t)b << 16);
        float aij = A[(i << 8) + j];
        float aji = A[(j << 8) + i];
        float v = fmaxf(aij, aji);
        if (j == i) v += 1.0f;

        float s = v;
        #pragma unroll
        for (int off = 32; off > 0; off >>= 1) s += __shfl_down(s, off);

        bool pred = v != 0.0f;
        unsigned long long m = __ballot(pred);
        int wid = j >> 6;
        if ((j & 63) == 0) { sm.na.part[wid] = s; sm.na.wcnt[wid] = (int)__popcll(m); }
        __syncthreads();
        int row = (b << 8) + i;
        if (j == 0) {
            float tt = sm.na.part[0] + sm.na.part[1] + sm.na.part[2] + sm.na.part[3];
            sm.na.sinv = tt > 0.0f ? 1.0f / tt : 0.0f;
            int o = 0;
            #pragma unroll
            for (int ww = 0; ww < 4; ++ww) { sm.na.woff[ww] = o; o += sm.na.wcnt[ww]; }
            annz[row] = o;
        }
        __syncthreads();
        if (pred) {
            int pos = sm.na.woff[wid] + (int)__popcll(m & ((1ull << (j & 63)) - 1ull));
            aval[row * 256 + pos] = v * sm.na.sinv;
            aidx[row * 256 + pos] = (uint16_t)j;
        }
    }
}

// ---- MFMA GEMM: C[M][N] = A[M][K] @ BT[N][K]^T ----------------------------
// 128x128 tile, BK=32, 256 threads = 4 waves (2x2), 16x16x32 bf16 MFMA.
// CONV: implicit im2col into xpad. SPLIT>1: K split over blockIdx.z,
// deterministic partials C[z][M][N] (no bias/relu).
template<bool CONV, int SPLIT>
__global__ __launch_bounds__(256)
void k_gemm(const uint16_t* __restrict__ A, const uint16_t* __restrict__ BT,
            float* __restrict__ C, const float* __restrict__ bias,
            int M, int N, int K, int relu)
{
    __shared__ __align__(16) uint16_t As[128 * 32];
    __shared__ __align__(16) uint16_t Bs[128 * 32];
    const int tid  = threadIdx.x;
    const int rt   = blockIdx.y * 128;
    const int ct   = blockIdx.x * 128;
    const int lane = tid & 63;
    const int wave = tid >> 6;
    const int wm   = (wave >> 1) * 64;
    const int wn   = (wave & 1) * 64;
    const int lm   = lane & 15;
    const int kq   = (lane >> 4) * 8;
    const int srow  = tid >> 2;
    const int skcol = (tid & 3) * 8;

    const int kchunk = K / SPLIT;
    const int kbeg   = (SPLIT > 1) ? blockIdx.z * kchunk : 0;
    const size_t MN  = (size_t)M * N;

    floatx4 acc[4][4] = {};

    for (int k0 = kbeg; k0 < kbeg + kchunk; k0 += 32) {
        #pragma unroll
        for (int ii = 0; ii < 2; ++ii) {
            int row = ii * 64 + srow;
            const uint16_t* gsrc;
            if (CONV) {
                int r  = rt + row;
                int b  = r >> 9;
                int t  = r & 511;
                int kk = k0 + skcol;
                int h  = kk >> 11;
                int ic = kk & 2047;
                gsrc = A + ((size_t)(b * 514 + t + h) << 11) + ic;
            } else {
                gsrc = A + (size_t)(rt + row) * K + k0 + skcol;
            }
            gload_lds16(gsrc, &As[ii * 2048 + tid * 8]);
            gload_lds16(BT + (size_t)(ct + row) * K + k0 + skcol, &Bs[ii * 2048 + tid * 8]);
        }
        __syncthreads();

        bf16x8 af[4], bfr[4];
        #pragma unroll
        for (int mt = 0; mt < 4; ++mt)
            af[mt] = *(const bf16x8*)&As[(wm + mt * 16 + lm) * 32 + kq];
        #pragma unroll
        for (int nt = 0; nt < 4; ++nt)
            bfr[nt] = *(const bf16x8*)&Bs[(wn + nt * 16 + lm) * 32 + kq];
        #pragma unroll
        for (int mt = 0; mt < 4; ++mt)
            #pragma unroll
            for (int nt = 0; nt < 4; ++nt)
                acc[mt][nt] = __builtin_amdgcn_mfma_f32_16x16x32_bf16(af[mt], bfr[nt], acc[mt][nt], 0, 0, 0);
        __syncthreads();
    }

    const int lq = lane >> 4;
    #pragma unroll
    for (int mt = 0; mt < 4; ++mt) {
        #pragma unroll
        for (int nt = 0; nt < 4; ++nt) {
            int col = ct + wn + nt * 16 + lm;
            float bv = (SPLIT == 1 && bias) ? bias[col] : 0.0f;
            #pragma unroll
            for (int r = 0; r < 4; ++r) {
                int row = rt + wm + mt * 16 + lq * 4 + r;
                if (SPLIT == 1) {
                    float v = acc[mt][nt][r] + bv;
                    if (relu) v = fmaxf(v, 0.0f);
                    C[(size_t)row * N + col] = v;
                } else {
                    C[blockIdx.z * MN + (size_t)row * N + col] = acc[mt][nt][r];
                }
            }
        }
    }
}

// ---- reduce 4 split-K partials: h = hp[0]+hp[1]+hp[2]+hp[3] ---------------
__global__ void k_reduce4(const float4* __restrict__ hp, float4* __restrict__ h) {
    int i = blockIdx.x * 256 + threadIdx.x;         // < 524288
    float4 a = hp[i], b = hp[i + 524288], c = hp[i + 1048576], d = hp[i + 1572864];
    float4 r;
    r.x = a.x + b.x + c.x + d.x;
    r.y = a.y + b.y + c.y + d.y;
    r.z = a.z + b.z + c.z + d.z;
    r.w = a.w + b.w + c.w + d.w;
    h[i] = r;
}

// ---- sparse a @ H (+bias, optional relu) over CSR, H f32 [1024][2048] -----
template<bool RELU, bool OUTBF>
__global__ void k_amul(const float* __restrict__ aval, const uint16_t* __restrict__ aidx,
                       const int* __restrict__ annz, const float* __restrict__ H,
                       const float* __restrict__ bias, void* __restrict__ outp)
{
    int f = blockIdx.x * 256 + threadIdx.x;
    int i = blockIdx.y;
    int b = blockIdx.z;
    int row = (b << 8) + i;
    __shared__ float vv[256];
    __shared__ int   jj[256];
    int n0 = annz[row];
    vv[threadIdx.x] = aval[row * 256 + threadIdx.x];
    jj[threadIdx.x] = aidx[row * 256 + threadIdx.x];
    __syncthreads();
    const float* Hb = H + ((size_t)b << 8) * 2048;
    float s = 0.0f;
    #pragma unroll 4
    for (int c = 0; c < n0; ++c)
        s += vv[c] * Hb[(size_t)jj[c] * 2048 + f];
    s += bias[f];
    if (RELU) s = fmaxf(s, 0.0f);
    size_t off = ((size_t)row) * 2048 + f;
    if (OUTBF) ((uint16_t*)outp)[off] = f2bf(s);
    else       ((float*)outp)[off]    = s;
}

// ---- launch ---------------------------------------------------------------

extern "C" void kernel_launch(void* const* d_in, const int* in_sizes, int n_in,
                              void* d_out, int out_size, void* d_ws, size_t ws_size,
                              hipStream_t stream)
{
    const float* x      = (const float*)d_in[0];
    const float* nodes  = (const float*)d_in[1];
    const float* adj    = (const float*)d_in[2];
    const float* conv_w = (const float*)d_in[3];
    const float* conv_b = (const float*)d_in[4];
    const float* W1     = (const float*)d_in[5];
    const float* b1     = (const float*)d_in[6];
    const float* W2     = (const float*)d_in[7];
    const float* b2     = (const float*)d_in[8];
    float* out = (float*)d_out;

    char* ws = (char*)d_ws;
    uint16_t* xpad   = (uint16_t*)(ws);                 // 25,288,704
    uint16_t* wmT    = (uint16_t*)(ws + 25288704);      // 25,165,824
    uint16_t* W1T    = (uint16_t*)(ws + 50454528);      // 8,388,608
    uint16_t* W2T    = (uint16_t*)(ws + 58843136);      // 8,388,608
    uint16_t* nodesb = (uint16_t*)(ws + 67231744);      // 4,194,304
    float*    aval   = (float*)   (ws + 71426048);      // 1,048,576
    float*    h1     = (float*)   (ws + 72474624);      // 8,388,608
    uint16_t* hb     = (uint16_t*)(ws + 80863232);      // 4,194,304
    float*    h2     = (float*)   (ws + 85057536);      // 8,388,608
    uint16_t* aidx   = (uint16_t*)(ws + 93446144);      // 524,288
    int*      annz   = (int*)     (ws + 93970432);      // 4,096
    // split-K partials [4][1024][2048] f32 = 32 MB, ALIASES xpad+wmT
    // (both dead once the conv GEMM has run; stream order guarantees that).
    float*    hp     = (float*)   (ws);

    k_prep<<<PREP_NA, 256, 0, stream>>>(x, (uint32_t*)xpad, conv_w, wmT,
                                        W1, W2, W1T, W2T,
                                        nodes, (uint32_t*)nodesb,
                                        adj, aval, aidx, annz);

    // feats = relu(conv(x) + conv_b)  -> d_out[0 : 12582912)
    k_gemm<true, 1><<<dim3(16, 48), 256, 0, stream>>>(xpad, wmT, out, conv_b, 6144, 2048, 6144, 1);
    // h1 = nodes @ W1 (split-K=4 partials, deterministic)
    k_gemm<false, 4><<<dim3(16, 8, 4), 256, 0, stream>>>(nodesb, W1T, hp, nullptr, 1024, 2048, 2048, 0);
    k_reduce4<<<2048, 256, 0, stream>>>((const float4*)hp, (float4*)h1);
    // h = relu(a @ h1 + b1) -> bf16
    k_amul<true, true><<<dim3(8, 256, 4), 256, 0, stream>>>(aval, aidx, annz, h1, b1, hb);
    // h2 = h @ W2 (split-K=4 partials)
    k_gemm<false, 4><<<dim3(16, 8, 4), 256, 0, stream>>>(hb, W2T, hp, nullptr, 1024, 2048, 2048, 0);
    k_reduce4<<<2048, 256, 0, stream>>>((const float4*)hp, (float4*)h2);
    // out = a @ h2 + b2 -> d_out[12582912 : )
    k_amul<false, false><<<dim3(8, 256, 4), 256, 0, stream>>>(aval, aidx, annz, h2, b2, out + 12582912);
}

// Round 4
// 470.078 us; speedup vs baseline: 1.3628x; 1.0108x over previous
//
#include <hip/hip_runtime.h>
#include <stdint.h>

typedef __bf16 bf16x8 __attribute__((ext_vector_type(8)));
typedef float floatx4 __attribute__((ext_vector_type(4)));

__device__ __forceinline__ void gload_lds16(const void* g, void* l) {
    __builtin_amdgcn_global_load_lds((const __attribute__((address_space(1))) void*)g,
                                     (__attribute__((address_space(3))) void*)l, 16, 0, 0);
}

__device__ __forceinline__ uint16_t f2bf(float f) {
    uint32_t u = __float_as_uint(f);
    u += 0x7fff + ((u >> 16) & 1);   // RNE
    return (uint16_t)(u >> 16);
}
__device__ __forceinline__ uint32_t f2bf2(float lo, float hi) {
    return (uint32_t)f2bf(lo) | ((uint32_t)f2bf(hi) << 16);
}

// ---- fused prep: norm_adj | wT | W-transpose | pad_x ----------------------
// Block ranges (irregular/latency-bound work first so it overlaps pad_x):
//   [0, 1024)           norm_adj   (4 * 256 rows)
//   [1024, 3072)        wT         (2048 output rows)
//   [3072, 5120)        W1/W2 transpose (2 * 32 * 32 tiles)
//   [5120, 29792)       pad_x      (12*514*1024 pairs / 256)
#define PREP_A  1024
#define PREP_W  3072
#define PREP_T  5120
#define PREP_N  29792

__global__ __launch_bounds__(256)
void k_prep(const float* __restrict__ x, uint32_t* __restrict__ xpad,
            const float* __restrict__ w, uint16_t* __restrict__ wT,
            const float* __restrict__ W1, const float* __restrict__ W2,
            uint16_t* __restrict__ W1T, uint16_t* __restrict__ W2T,
            const float* __restrict__ adj, float* __restrict__ aval,
            uint16_t* __restrict__ aidx, int* __restrict__ annz)
{
    __shared__ union {
        float wbuf[6144];
        float tile[64][65];
        struct { float part[4]; int wcnt[4]; int woff[4]; float sinv; } na;
    } sm;
    const int bid = blockIdx.x;
    const int tid = threadIdx.x;

    if (bid < PREP_A) {
        // ---- a = rownorm(max(adj,adj^T) + I), CSR-compacted
        int i = bid & 255, b = bid >> 8, j = tid;
        const float* A = adj + ((size_t)b << 16);
        float aij = A[(i << 8) + j];
        float aji = A[(j << 8) + i];
        float v = fmaxf(aij, aji);
        if (j == i) v += 1.0f;

        float s = v;
        #pragma unroll
        for (int off = 32; off > 0; off >>= 1) s += __shfl_down(s, off);

        bool pred = v != 0.0f;
        unsigned long long m = __ballot(pred);
        int wid = j >> 6;
        if ((j & 63) == 0) { sm.na.part[wid] = s; sm.na.wcnt[wid] = (int)__popcll(m); }
        __syncthreads();
        int row = (b << 8) + i;
        if (j == 0) {
            float tt = sm.na.part[0] + sm.na.part[1] + sm.na.part[2] + sm.na.part[3];
            sm.na.sinv = tt > 0.0f ? 1.0f / tt : 0.0f;
            int o = 0;
            #pragma unroll
            for (int ww = 0; ww < 4; ++ww) { sm.na.woff[ww] = o; o += sm.na.wcnt[ww]; }
            annz[row] = o;
        }
        __syncthreads();
        if (pred) {
            int pos = sm.na.woff[wid] + (int)__popcll(m & ((1ull << (j & 63)) - 1ull));
            aval[row * 256 + pos] = v * sm.na.sinv;
            aidx[row * 256 + pos] = (uint16_t)j;
        }
    } else if (bid < PREP_W) {
        // ---- conv_w [o][i][h] -> wT [o][h*2048+i] bf16 (LDS-staged)
        int o = bid - PREP_A;
        const float* src = w + (size_t)o * 6144;
        uint16_t*    dst = wT + (size_t)o * 6144;
        #pragma unroll
        for (int it = 0; it < 24; ++it)
            sm.wbuf[it * 256 + tid] = src[it * 256 + tid];
        __syncthreads();
        #pragma unroll
        for (int h = 0; h < 3; ++h)
            #pragma unroll
            for (int c = 0; c < 8; ++c) {
                int i = c * 256 + tid;
                dst[h * 2048 + i] = f2bf(sm.wbuf[i * 3 + h]);  // stride-3: conflict-free
            }
    } else if (bid < PREP_T) {
        // ---- W1/W2 [2048][2048] -> bf16 transpose
        int t  = bid - PREP_W;
        int z  = t >> 10;
        int by = (t >> 5) & 31;
        int bx = t & 31;
        const float* src = z ? W2 : W1;
        uint16_t*    dst = z ? W2T : W1T;
        int tx = tid & 63, ty = tid >> 6;
        for (int rr = ty; rr < 64; rr += 4)
            sm.tile[rr][tx] = src[(size_t)(by * 64 + rr) * 2048 + bx * 64 + tx];
        __syncthreads();
        for (int rr = ty; rr < 64; rr += 4)
            dst[(size_t)(bx * 64 + rr) * 2048 + by * 64 + tx] = f2bf(sm.tile[tx][rr]);
    } else {
        // ---- x [12,512,2048] f32 -> xpad [12,514,2048] bf16 (zero pad rows)
        int idx2 = (bid - PREP_T) * 256 + tid;
        int i2   = idx2 & 1023;
        int tmp  = idx2 >> 10;                      // b*514 + tt
        int b    = tmp / 514;
        int tt   = tmp - b * 514;
        float lo = 0.0f, hi = 0.0f;
        if (tt >= 1 && tt <= 512) {
            const float* s = x + ((size_t)(b * 512 + tt - 1) << 11) + i2 * 2;
            lo = s[0]; hi = s[1];
        }
        xpad[idx2] = f2bf2(lo, hi);
    }
}

// ---- MFMA GEMM 128x128: C[M][N] = A[M][K] @ BT[N][K]^T + bias (+relu) -----
// BK=32, 256 threads = 4 waves (2x2), 16x16x32 bf16 MFMA.
// CONV: im2col folds into a hoisted per-thread row base (inner loop is plain).
template<bool CONV, bool RELU>
__global__ __launch_bounds__(256)
void k_gemm(const uint16_t* __restrict__ A, const uint16_t* __restrict__ BT,
            float* __restrict__ C, const float* __restrict__ bias,
            int N, int K)
{
    __shared__ __align__(16) uint16_t As[128 * 32];
    __shared__ __align__(16) uint16_t Bs[128 * 32];
    const int tid  = threadIdx.x;
    const int rt   = blockIdx.y * 128;
    const int ct   = blockIdx.x * 128;
    const int lane = tid & 63;
    const int wave = tid >> 6;
    const int wm   = (wave >> 1) * 64;
    const int wn   = (wave & 1) * 64;
    const int lm   = lane & 15;
    const int kq   = (lane >> 4) * 8;
    const int srow  = tid >> 2;          // 0..63
    const int skcol = (tid & 3) * 8;     // 0,8,16,24

    // hoisted staging bases: im2col  ((b*514+t+h)<<11)+ic == ((b*514+t)<<11)+kk
    size_t abase[2], bbase[2];
    #pragma unroll
    for (int ii = 0; ii < 2; ++ii) {
        int row = ii * 64 + srow;
        if (CONV) {
            int r = rt + row;
            int b = r >> 9;
            int t = r & 511;
            abase[ii] = ((size_t)(b * 514 + t) << 11) + skcol;
        } else {
            abase[ii] = (size_t)(rt + row) * K + skcol;
        }
        bbase[ii] = (size_t)(ct + row) * K + skcol;
    }

    floatx4 acc[4][4] = {};

    for (int k0 = 0; k0 < K; k0 += 32) {
        #pragma unroll
        for (int ii = 0; ii < 2; ++ii) {
            gload_lds16(A  + abase[ii] + k0, &As[ii * 2048 + tid * 8]);
            gload_lds16(BT + bbase[ii] + k0, &Bs[ii * 2048 + tid * 8]);
        }
        __syncthreads();

        bf16x8 af[4], bfr[4];
        #pragma unroll
        for (int mt = 0; mt < 4; ++mt)
            af[mt] = *(const bf16x8*)&As[(wm + mt * 16 + lm) * 32 + kq];
        #pragma unroll
        for (int nt = 0; nt < 4; ++nt)
            bfr[nt] = *(const bf16x8*)&Bs[(wn + nt * 16 + lm) * 32 + kq];
        #pragma unroll
        for (int mt = 0; mt < 4; ++mt)
            #pragma unroll
            for (int nt = 0; nt < 4; ++nt)
                acc[mt][nt] = __builtin_amdgcn_mfma_f32_16x16x32_bf16(af[mt], bfr[nt], acc[mt][nt], 0, 0, 0);
        __syncthreads();
    }

    const int lq = lane >> 4;
    #pragma unroll
    for (int mt = 0; mt < 4; ++mt) {
        #pragma unroll
        for (int nt = 0; nt < 4; ++nt) {
            int col = ct + wn + nt * 16 + lm;
            float bv = bias[col];
            #pragma unroll
            for (int r = 0; r < 4; ++r) {
                int row = rt + wm + mt * 16 + lq * 4 + r;
                float v = acc[mt][nt][r] + bv;
                if (RELU) v = fmaxf(v, 0.0f);
                C[(size_t)row * N + col] = v;
            }
        }
    }
}

// ---- MFMA GEMM 64x64 (occupancy-friendly, no split-K needed) --------------
// grid (N/64, M/64); 256 threads = 4 waves 2x2, each wave 32x32 (2x2 MFMA tiles).
template<bool RELU>
__global__ __launch_bounds__(256)
void k_gemm64(const uint16_t* __restrict__ A, const uint16_t* __restrict__ BT,
              float* __restrict__ C, const float* __restrict__ bias,
              int N, int K)
{
    __shared__ __align__(16) uint16_t As[64 * 32];
    __shared__ __align__(16) uint16_t Bs[64 * 32];
    const int tid  = threadIdx.x;
    const int rt   = blockIdx.y * 64;
    const int ct   = blockIdx.x * 64;
    const int lane = tid & 63;
    const int wave = tid >> 6;
    const int wm   = (wave >> 1) * 32;
    const int wn   = (wave & 1) * 32;
    const int lm   = lane & 15;
    const int kq   = (lane >> 4) * 8;
    const int srow  = tid >> 2;
    const int skcol = (tid & 3) * 8;

    const size_t abase = (size_t)(rt + srow) * K + skcol;
    const size_t bbase = (size_t)(ct + srow) * K + skcol;

    floatx4 acc[2][2] = {};

    for (int k0 = 0; k0 < K; k0 += 32) {
        gload_lds16(A  + abase + k0, &As[tid * 8]);
        gload_lds16(BT + bbase + k0, &Bs[tid * 8]);
        __syncthreads();

        bf16x8 af[2], bfr[2];
        #pragma unroll
        for (int mt = 0; mt < 2; ++mt)
            af[mt] = *(const bf16x8*)&As[(wm + mt * 16 + lm) * 32 + kq];
        #pragma unroll
        for (int nt = 0; nt < 2; ++nt)
            bfr[nt] = *(const bf16x8*)&Bs[(wn + nt * 16 + lm) * 32 + kq];
        #pragma unroll
        for (int mt = 0; mt < 2; ++mt)
            #pragma unroll
            for (int nt = 0; nt < 2; ++nt)
                acc[mt][nt] = __builtin_amdgcn_mfma_f32_16x16x32_bf16(af[mt], bfr[nt], acc[mt][nt], 0, 0, 0);
        __syncthreads();
    }

    const int lq = lane >> 4;
    #pragma unroll
    for (int mt = 0; mt < 2; ++mt) {
        #pragma unroll
        for (int nt = 0; nt < 2; ++nt) {
            int col = ct + wn + nt * 16 + lm;
            float bv = bias[col];
            #pragma unroll
            for (int r = 0; r < 4; ++r) {
                int row = rt + wm + mt * 16 + lq * 4 + r;
                float v = acc[mt][nt][r] + bv;
                if (RELU) v = fmaxf(v, 0.0f);
                C[(size_t)row * N + col] = v;
            }
        }
    }
}

// ---- sparse a @ H over CSR: out_bf16 = a @ H (no bias/relu) ---------------
// H f32 [4][256][2048]; grid (8, 256, 4).
__global__ void k_amul(const float* __restrict__ aval, const uint16_t* __restrict__ aidx,
                       const int* __restrict__ annz, const float* __restrict__ H,
                       uint16_t* __restrict__ outp)
{
    int f = blockIdx.x * 256 + threadIdx.x;
    int i = blockIdx.y;
    int b = blockIdx.z;
    int row = (b << 8) + i;
    __shared__ float vv[256];
    __shared__ int   jj[256];
    int n0 = annz[row];
    vv[threadIdx.x] = aval[row * 256 + threadIdx.x];
    jj[threadIdx.x] = aidx[row * 256 + threadIdx.x];
    __syncthreads();
    const float* Hb = H + ((size_t)b << 8) * 2048;
    float s = 0.0f;
    #pragma unroll 4
    for (int c = 0; c < n0; ++c)
        s += vv[c] * Hb[(size_t)jj[c] * 2048 + f];
    outp[(size_t)row * 2048 + f] = f2bf(s);
}

// ---- launch ---------------------------------------------------------------

extern "C" void kernel_launch(void* const* d_in, const int* in_sizes, int n_in,
                              void* d_out, int out_size, void* d_ws, size_t ws_size,
                              hipStream_t stream)
{
    const float* x      = (const float*)d_in[0];
    const float* nodes  = (const float*)d_in[1];
    const float* adj    = (const float*)d_in[2];
    const float* conv_w = (const float*)d_in[3];
    const float* conv_b = (const float*)d_in[4];
    const float* W1     = (const float*)d_in[5];
    const float* b1     = (const float*)d_in[6];
    const float* W2     = (const float*)d_in[7];
    const float* b2     = (const float*)d_in[8];
    float* out = (float*)d_out;

    char* ws = (char*)d_ws;
    uint16_t* xpad   = (uint16_t*)(ws);                 // 25,288,704
    uint16_t* wmT    = (uint16_t*)(ws + 25288704);      // 25,165,824
    uint16_t* W1T    = (uint16_t*)(ws + 50454528);      // 8,388,608
    uint16_t* W2T    = (uint16_t*)(ws + 58843136);      // 8,388,608
    float*    aval   = (float*)   (ws + 67231744);      // 1,048,576
    uint16_t* aidx   = (uint16_t*)(ws + 68280320);      // 524,288
    int*      annz   = (int*)     (ws + 68804608);      // 4,096
    uint16_t* gbf    = (uint16_t*)(ws + 68808704);      // 4,194,304  a@nodes (bf16)
    float*    h      = (float*)   (ws + 73003008);      // 8,388,608  relu(g@W1+b1)
    uint16_t* ahb    = (uint16_t*)(ws + 81391616);      // 4,194,304  a@h (bf16)

    k_prep<<<PREP_N, 256, 0, stream>>>(x, (uint32_t*)xpad, conv_w, wmT,
                                       W1, W2, W1T, W2T,
                                       adj, aval, aidx, annz);

    // feats = relu(conv(x) + conv_b)  -> d_out[0 : 12582912)
    k_gemm<true, true><<<dim3(16, 48), 256, 0, stream>>>(xpad, wmT, out, conv_b, 2048, 6144);

    // GCN via associativity: a@(nodes@W1) == (a@nodes)@W1, a@(h@W2) == (a@h)@W2
    k_amul<<<dim3(8, 256, 4), 256, 0, stream>>>(aval, aidx, annz, nodes, gbf);
    k_gemm64<true><<<dim3(32, 16), 256, 0, stream>>>(gbf, W1T, h, b1, 2048, 2048);
    k_amul<<<dim3(8, 256, 4), 256, 0, stream>>>(aval, aidx, annz, h, ahb);
    k_gemm64<false><<<dim3(32, 16), 256, 0, stream>>>(ahb, W2T, out + 12582912, b2, 2048, 2048);
}

// Round 5
// 427.511 us; speedup vs baseline: 1.4985x; 1.0996x over previous
//
#include <hip/hip_runtime.h>
#include <stdint.h>

typedef __bf16 bf16x8 __attribute__((ext_vector_type(8)));
typedef float floatx4 __attribute__((ext_vector_type(4)));

__device__ __forceinline__ void gload_lds16(const void* g, void* l) {
    __builtin_amdgcn_global_load_lds((const __attribute__((address_space(1))) void*)g,
                                     (__attribute__((address_space(3))) void*)l, 16, 0, 0);
}

__device__ __forceinline__ uint16_t f2bf(float f) {
    uint32_t u = __float_as_uint(f);
    u += 0x7fff + ((u >> 16) & 1);   // RNE
    return (uint16_t)(u >> 16);
}
__device__ __forceinline__ uint32_t f2bf2(float lo, float hi) {
    return (uint32_t)f2bf(lo) | ((uint32_t)f2bf(hi) << 16);
}

// ---- fused normalize_adj + sparse row gather ------------------------------
// One block per (b,i) row: build a-row from adj on the fly (rownorm(max(adj,
// adj^T)+I)), ballot-compact nonzeros to LDS, then out[row] = sum a_ij*H[j].
// out is bf16 [1024][2048]; 8 cols/thread.
struct AmulSM {
    float vv[256];
    int   jj[256];
    float part[4];
    int   wcnt[4];
    int   woff[4];
    float sinv;
    int   n0;
};

__device__ __forceinline__ void amul_body(const float* __restrict__ adj,
                                          const float* __restrict__ H,
                                          uint16_t* __restrict__ outp,
                                          int b, int i, int tid, AmulSM* sm)
{
    const float* A = adj + ((size_t)b << 16);
    float aij = A[(i << 8) + tid];
    float aji = A[(tid << 8) + i];
    float v = fmaxf(aij, aji);
    if (tid == i) v += 1.0f;

    float s = v;
    #pragma unroll
    for (int off = 32; off > 0; off >>= 1) s += __shfl_down(s, off);

    bool pred = v != 0.0f;
    unsigned long long m = __ballot(pred);
    int wid = tid >> 6;
    if ((tid & 63) == 0) { sm->part[wid] = s; sm->wcnt[wid] = (int)__popcll(m); }
    __syncthreads();
    if (tid == 0) {
        float t = sm->part[0] + sm->part[1] + sm->part[2] + sm->part[3];
        sm->sinv = t > 0.0f ? 1.0f / t : 0.0f;
        int o = 0;
        #pragma unroll
        for (int w = 0; w < 4; ++w) { sm->woff[w] = o; o += sm->wcnt[w]; }
        sm->n0 = o;
    }
    __syncthreads();
    if (pred) {
        int pos = sm->woff[wid] + (int)__popcll(m & ((1ull << (tid & 63)) - 1ull));
        sm->vv[pos] = v * sm->sinv;
        sm->jj[pos] = tid;
    }
    __syncthreads();

    const int n0 = sm->n0;
    const int f0 = tid * 8;
    const float* Hb = H + (((size_t)b) << 8) * 2048;
    float acc[8] = {};
    for (int c = 0; c < n0; ++c) {
        float av = sm->vv[c];
        const float* hp = Hb + (size_t)sm->jj[c] * 2048 + f0;
        float4 p = *(const float4*)hp;
        float4 q = *(const float4*)(hp + 4);
        acc[0] += av * p.x; acc[1] += av * p.y; acc[2] += av * p.z; acc[3] += av * p.w;
        acc[4] += av * q.x; acc[5] += av * q.y; acc[6] += av * q.z; acc[7] += av * q.w;
    }
    uint4 o;
    o.x = f2bf2(acc[0], acc[1]);
    o.y = f2bf2(acc[2], acc[3]);
    o.z = f2bf2(acc[4], acc[5]);
    o.w = f2bf2(acc[6], acc[7]);
    *(uint4*)(outp + (((size_t)b << 8) + i) * 2048 + f0) = o;
}

// ---- dispatch 1: amul#1 | wT | W-transposes | pad_x (inputs only) ---------
//   [0, 1024)        amul#1: gbf = a @ nodes (bf16)
//   [1024, 3072)     conv_w -> wT bf16
//   [3072, 5120)     W1/W2 -> bf16 transpose
//   [5120, 29792)    pad_x
#define PR_AM 1024
#define PR_W  3072
#define PR_T  5120
#define PR_N  29792

__global__ __launch_bounds__(256)
void k_prep(const float* __restrict__ x, uint32_t* __restrict__ xpad,
            const float* __restrict__ w, uint16_t* __restrict__ wT,
            const float* __restrict__ W1, const float* __restrict__ W2,
            uint16_t* __restrict__ W1T, uint16_t* __restrict__ W2T,
            const float* __restrict__ adj, const float* __restrict__ nodes,
            uint16_t* __restrict__ gbf)
{
    __shared__ union {
        float  wbuf[6144];
        float  tile[64][65];
        AmulSM am;
    } sm;
    const int bid = blockIdx.x;
    const int tid = threadIdx.x;

    if (bid < PR_AM) {
        amul_body(adj, nodes, gbf, bid >> 8, bid & 255, tid, &sm.am);
    } else if (bid < PR_W) {
        // conv_w [o][i][h] -> wT [o][h*2048+i] bf16 (LDS-staged)
        int o = bid - PR_AM;
        const float* src = w + (size_t)o * 6144;
        uint16_t*    dst = wT + (size_t)o * 6144;
        #pragma unroll
        for (int it = 0; it < 24; ++it)
            sm.wbuf[it * 256 + tid] = src[it * 256 + tid];
        __syncthreads();
        #pragma unroll
        for (int h = 0; h < 3; ++h)
            #pragma unroll
            for (int c = 0; c < 8; ++c) {
                int i = c * 256 + tid;
                dst[h * 2048 + i] = f2bf(sm.wbuf[i * 3 + h]);  // stride-3: conflict-free
            }
    } else if (bid < PR_T) {
        // W1/W2 [2048][2048] -> bf16 transpose
        int t  = bid - PR_W;
        int z  = t >> 10;
        int by = (t >> 5) & 31;
        int bx = t & 31;
        const float* src = z ? W2 : W1;
        uint16_t*    dst = z ? W2T : W1T;
        int tx = tid & 63, ty = tid >> 6;
        for (int rr = ty; rr < 64; rr += 4)
            sm.tile[rr][tx] = src[(size_t)(by * 64 + rr) * 2048 + bx * 64 + tx];
        __syncthreads();
        for (int rr = ty; rr < 64; rr += 4)
            dst[(size_t)(bx * 64 + rr) * 2048 + by * 64 + tx] = f2bf(sm.tile[tx][rr]);
    } else {
        // x [12,512,2048] f32 -> xpad [12,514,2048] bf16 (zero pad rows)
        int idx2 = (bid - PR_T) * 256 + tid;
        int i2   = idx2 & 1023;
        int tmp  = idx2 >> 10;                      // b*514 + tt
        int b    = tmp / 514;
        int tt   = tmp - b * 514;
        float lo = 0.0f, hi = 0.0f;
        if (tt >= 1 && tt <= 512) {
            const float* s = x + ((size_t)(b * 512 + tt - 1) << 11) + i2 * 2;
            lo = s[0]; hi = s[1];
        }
        xpad[idx2] = f2bf2(lo, hi);
    }
}

// ---- dispatch 2: conv GEMM (768 blocks) || gemm64#1 (512 blocks) ----------
// conv: 128x128 tile, BK=32, implicit im2col, relu(conv+b) -> out f32.
// gemm64#1: h = relu(gbf @ W1T^T + b1) -> f32, 64x64 tile.
__global__ __launch_bounds__(256)
void k_big(const uint16_t* __restrict__ xpad, const uint16_t* __restrict__ wmT,
           float* __restrict__ feats, const float* __restrict__ conv_b,
           const uint16_t* __restrict__ gbf, const uint16_t* __restrict__ W1T,
           float* __restrict__ h, const float* __restrict__ b1)
{
    __shared__ __align__(16) uint16_t lds[8192];    // conv: As[4096]+Bs[4096]; g64: As[2048]+Bs[2048]
    const int bid  = blockIdx.x;
    const int tid  = threadIdx.x;
    const int lane = tid & 63;
    const int wave = tid >> 6;
    const int lm   = lane & 15;
    const int kq   = (lane >> 4) * 8;
    const int lq   = lane >> 4;
    const int srow  = tid >> 2;
    const int skcol = (tid & 3) * 8;

    if (bid < 768) {
        // ---------------- conv GEMM 128x128, K=6144 ----------------
        uint16_t* As = lds;
        uint16_t* Bs = lds + 4096;
        const int rt = (bid >> 4) * 128;
        const int ct = (bid & 15) * 128;
        const int wm = (wave >> 1) * 64;
        const int wn = (wave & 1) * 64;

        floatx4 acc[4][4] = {};

        for (int k0 = 0; k0 < 6144; k0 += 32) {
            #pragma unroll
            for (int ii = 0; ii < 2; ++ii) {
                int row = ii * 64 + srow;
                int r  = rt + row;
                int b  = r >> 9;
                int t  = r & 511;
                int kk = k0 + skcol;
                int hh = kk >> 11;
                int ic = kk & 2047;
                gload_lds16(xpad + ((size_t)(b * 514 + t + hh) << 11) + ic,
                            &As[ii * 2048 + tid * 8]);
                gload_lds16(wmT + (size_t)(ct + row) * 6144 + k0 + skcol,
                            &Bs[ii * 2048 + tid * 8]);
            }
            __syncthreads();

            bf16x8 af[4], bfr[4];
            #pragma unroll
            for (int mt = 0; mt < 4; ++mt)
                af[mt] = *(const bf16x8*)&As[(wm + mt * 16 + lm) * 32 + kq];
            #pragma unroll
            for (int nt = 0; nt < 4; ++nt)
                bfr[nt] = *(const bf16x8*)&Bs[(wn + nt * 16 + lm) * 32 + kq];
            #pragma unroll
            for (int mt = 0; mt < 4; ++mt)
                #pragma unroll
                for (int nt = 0; nt < 4; ++nt)
                    acc[mt][nt] = __builtin_amdgcn_mfma_f32_16x16x32_bf16(af[mt], bfr[nt], acc[mt][nt], 0, 0, 0);
            __syncthreads();
        }

        #pragma unroll
        for (int mt = 0; mt < 4; ++mt)
            #pragma unroll
            for (int nt = 0; nt < 4; ++nt) {
                int col = ct + wn + nt * 16 + lm;
                float bv = conv_b[col];
                #pragma unroll
                for (int r = 0; r < 4; ++r) {
                    int row = rt + wm + mt * 16 + lq * 4 + r;
                    feats[(size_t)row * 2048 + col] = fmaxf(acc[mt][nt][r] + bv, 0.0f);
                }
            }
    } else {
        // ---------------- gemm64#1: 64x64, K=2048 ----------------
        uint16_t* As = lds;
        uint16_t* Bs = lds + 2048;
        const int t  = bid - 768;
        const int rt = (t >> 5) * 64;
        const int ct = (t & 31) * 64;
        const int wm = (wave >> 1) * 32;
        const int wn = (wave & 1) * 32;

        const size_t abase = (size_t)(rt + srow) * 2048 + skcol;
        const size_t bbase = (size_t)(ct + srow) * 2048 + skcol;

        floatx4 acc[2][2] = {};

        for (int k0 = 0; k0 < 2048; k0 += 32) {
            gload_lds16(gbf + abase + k0, &As[tid * 8]);
            gload_lds16(W1T + bbase + k0, &Bs[tid * 8]);
            __syncthreads();

            bf16x8 af[2], bfr[2];
            #pragma unroll
            for (int mt = 0; mt < 2; ++mt)
                af[mt] = *(const bf16x8*)&As[(wm + mt * 16 + lm) * 32 + kq];
            #pragma unroll
            for (int nt = 0; nt < 2; ++nt)
                bfr[nt] = *(const bf16x8*)&Bs[(wn + nt * 16 + lm) * 32 + kq];
            #pragma unroll
            for (int mt = 0; mt < 2; ++mt)
                #pragma unroll
                for (int nt = 0; nt < 2; ++nt)
                    acc[mt][nt] = __builtin_amdgcn_mfma_f32_16x16x32_bf16(af[mt], bfr[nt], acc[mt][nt], 0, 0, 0);
            __syncthreads();
        }

        #pragma unroll
        for (int mt = 0; mt < 2; ++mt)
            #pragma unroll
            for (int nt = 0; nt < 2; ++nt) {
                int col = ct + wn + nt * 16 + lm;
                float bv = b1[col];
                #pragma unroll
                for (int r = 0; r < 4; ++r) {
                    int row = rt + wm + mt * 16 + lq * 4 + r;
                    h[(size_t)row * 2048 + col] = fmaxf(acc[mt][nt][r] + bv, 0.0f);
                }
            }
    }
}

// ---- dispatch 3: ahb = a @ h (bf16), normalize folded in ------------------
__global__ __launch_bounds__(256)
void k_amul(const float* __restrict__ adj, const float* __restrict__ H,
            uint16_t* __restrict__ outp)
{
    __shared__ AmulSM sm;
    amul_body(adj, H, outp, blockIdx.x >> 8, blockIdx.x & 255, threadIdx.x, &sm);
}

// ---- dispatch 4: out = ahb @ W2T^T + b2 (64x64 tiles) ---------------------
__global__ __launch_bounds__(256)
void k_gemm64(const uint16_t* __restrict__ A, const uint16_t* __restrict__ BT,
              float* __restrict__ C, const float* __restrict__ bias)
{
    __shared__ __align__(16) uint16_t As[64 * 32];
    __shared__ __align__(16) uint16_t Bs[64 * 32];
    const int tid  = threadIdx.x;
    const int rt   = blockIdx.y * 64;
    const int ct   = blockIdx.x * 64;
    const int lane = tid & 63;
    const int wave = tid >> 6;
    const int wm   = (wave >> 1) * 32;
    const int wn   = (wave & 1) * 32;
    const int lm   = lane & 15;
    const int kq   = (lane >> 4) * 8;
    const int srow  = tid >> 2;
    const int skcol = (tid & 3) * 8;

    const size_t abase = (size_t)(rt + srow) * 2048 + skcol;
    const size_t bbase = (size_t)(ct + srow) * 2048 + skcol;

    floatx4 acc[2][2] = {};

    for (int k0 = 0; k0 < 2048; k0 += 32) {
        gload_lds16(A  + abase + k0, &As[tid * 8]);
        gload_lds16(BT + bbase + k0, &Bs[tid * 8]);
        __syncthreads();

        bf16x8 af[2], bfr[2];
        #pragma unroll
        for (int mt = 0; mt < 2; ++mt)
            af[mt] = *(const bf16x8*)&As[(wm + mt * 16 + lm) * 32 + kq];
        #pragma unroll
        for (int nt = 0; nt < 2; ++nt)
            bfr[nt] = *(const bf16x8*)&Bs[(wn + nt * 16 + lm) * 32 + kq];
        #pragma unroll
        for (int mt = 0; mt < 2; ++mt)
            #pragma unroll
            for (int nt = 0; nt < 2; ++nt)
                acc[mt][nt] = __builtin_amdgcn_mfma_f32_16x16x32_bf16(af[mt], bfr[nt], acc[mt][nt], 0, 0, 0);
        __syncthreads();
    }

    const int lq = lane >> 4;
    #pragma unroll
    for (int mt = 0; mt < 2; ++mt)
        #pragma unroll
        for (int nt = 0; nt < 2; ++nt) {
            int col = ct + wn + nt * 16 + lm;
            float bv = bias[col];
            #pragma unroll
            for (int r = 0; r < 4; ++r) {
                int row = rt + wm + mt * 16 + lq * 4 + r;
                C[(size_t)row * 2048 + col] = acc[mt][nt][r] + bv;
            }
        }
}

// ---- launch ---------------------------------------------------------------

extern "C" void kernel_launch(void* const* d_in, const int* in_sizes, int n_in,
                              void* d_out, int out_size, void* d_ws, size_t ws_size,
                              hipStream_t stream)
{
    const float* x      = (const float*)d_in[0];
    const float* nodes  = (const float*)d_in[1];
    const float* adj    = (const float*)d_in[2];
    const float* conv_w = (const float*)d_in[3];
    const float* conv_b = (const float*)d_in[4];
    const float* W1     = (const float*)d_in[5];
    const float* b1     = (const float*)d_in[6];
    const float* W2     = (const float*)d_in[7];
    const float* b2     = (const float*)d_in[8];
    float* out = (float*)d_out;

    char* ws = (char*)d_ws;
    uint16_t* xpad   = (uint16_t*)(ws);                 // 25,288,704
    uint16_t* wmT    = (uint16_t*)(ws + 25288704);      // 25,165,824
    uint16_t* W1T    = (uint16_t*)(ws + 50454528);      // 8,388,608
    uint16_t* W2T    = (uint16_t*)(ws + 58843136);      // 8,388,608
    uint16_t* gbf    = (uint16_t*)(ws + 67231744);      // 4,194,304  a@nodes (bf16)
    float*    h      = (float*)   (ws + 71426048);      // 8,388,608  relu(gbf@W1+b1)
    uint16_t* ahb    = (uint16_t*)(ws + 79814656);      // 4,194,304  a@h (bf16)

    // d1: everything that depends only on inputs (amul#1 has normalize folded in)
    k_prep<<<PR_N, 256, 0, stream>>>(x, (uint32_t*)xpad, conv_w, wmT,
                                     W1, W2, W1T, W2T, adj, nodes, gbf);
    // d2: conv GEMM || gemm64#1 co-scheduled
    k_big<<<1280, 256, 0, stream>>>(xpad, wmT, out, conv_b, gbf, W1T, h, b1);
    // d3: ahb = a @ h
    k_amul<<<1024, 256, 0, stream>>>(adj, h, ahb);
    // d4: out_gcn = ahb @ W2 + b2
    k_gemm64<<<dim3(32, 16), 256, 0, stream>>>(ahb, W2T, out + 12582912, b2);
}